// Round 4
// baseline (254.772 us; speedup 1.0000x reference)
//
#include <hip/hip_runtime.h>

// ClusterDiceLoss: segmented dice over 64 clusters of a 256^3 volume.
// R1 115us: latency-bound (VGPR=16, 1 load in flight). R2 432us: 8MB-strided
// batch aliased channels. R3 76us: contiguous chunks, but VGPR=36 shows the
// compiler sank the 12 batched loads -> MLP never materialized.
// R4: explicit 2-buffer register pipeline (load set s+1 while atomics of set s)
// + __launch_bounds__(256,4) so 96 VGPRs of load data can stay in flight.

#define NSEG 65          // clusters 0..64 (0 = background, dropped)
#define NWAVES 4         // 256 threads / wave64
#define BLOCKS 1024
#define THREADS 256
#define SETSPAN (4 * THREADS)   // float4 groups per set per block

// Pack per-element contribution into one u64: inter<<42 | sum_p<<21 | sum_t.
// Global per-segment field totals ~260k << 2^21, so fields never carry.
__device__ __forceinline__ unsigned long long pack_contrib(float p, float t) {
    unsigned long long sp = (p != 0.0f) ? 1ull : 0ull;
    unsigned long long st = (t != 0.0f) ? 1ull : 0ull;
    return ((sp & st) << 42) | (sp << 21) | st;
}

__global__ __launch_bounds__(THREADS, 4) void seg_count_kernel(
    const float* __restrict__ pred,
    const float* __restrict__ target,
    const int* __restrict__ labels,
    unsigned long long* __restrict__ g_counts,   // [NSEG] packed, pre-zeroed
    int n)
{
    __shared__ unsigned long long s_cnt[NWAVES][NSEG];
    const int tid = threadIdx.x;
    const int wave = tid >> 6;

    for (int i = tid; i < NWAVES * NSEG; i += THREADS)
        ((unsigned long long*)s_cnt)[i] = 0ull;
    __syncthreads();

    const int n_vec = n >> 2;  // float4 groups
    const float4* __restrict__ p4 = (const float4*)pred;
    const float4* __restrict__ t4 = (const float4*)target;
    const int4*   __restrict__ l4 = (const int4*)labels;

    const int chunk = (n_vec + (int)gridDim.x - 1) / (int)gridDim.x;
    const int base = blockIdx.x * chunk;
    const int end = min(base + chunk, n_vec);
    const int nsets = (end - base) / SETSPAN;   // complete sets

    float4 pr[2][4], tr[2][4];
    int4   lr[2][4];

    auto load_set = [&](int b, int at) {
        #pragma unroll
        for (int g = 0; g < 4; ++g) {
            pr[b][g] = p4[at + g * THREADS];
            tr[b][g] = t4[at + g * THREADS];
            lr[b][g] = l4[at + g * THREADS];
        }
    };
    auto proc_set = [&](int b) {
        #pragma unroll
        for (int g = 0; g < 4; ++g) {
            atomicAdd(&s_cnt[wave][lr[b][g].x], pack_contrib(pr[b][g].x, tr[b][g].x));
            atomicAdd(&s_cnt[wave][lr[b][g].y], pack_contrib(pr[b][g].y, tr[b][g].y));
            atomicAdd(&s_cnt[wave][lr[b][g].z], pack_contrib(pr[b][g].z, tr[b][g].z));
            atomicAdd(&s_cnt[wave][lr[b][g].w], pack_contrib(pr[b][g].w, tr[b][g].w));
        }
    };

    int idx = base + tid;
    if (nsets > 0) {
        load_set(0, idx);
        int buf = 0;
        for (int s = 0; s < nsets - 1; ++s) {
            load_set(buf ^ 1, idx + SETSPAN);   // prefetch next set
            proc_set(buf);                       // atomics for current set
            idx += SETSPAN;
            buf ^= 1;
        }
        proc_set(buf);
    }
    // remainder groups (incomplete set at end of chunk)
    for (idx = base + nsets * SETSPAN + tid; idx < end; idx += THREADS) {
        float4 p = p4[idx];
        float4 t = t4[idx];
        int4   l = l4[idx];
        atomicAdd(&s_cnt[wave][l.x], pack_contrib(p.x, t.x));
        atomicAdd(&s_cnt[wave][l.y], pack_contrib(p.y, t.y));
        atomicAdd(&s_cnt[wave][l.z], pack_contrib(p.z, t.z));
        atomicAdd(&s_cnt[wave][l.w], pack_contrib(p.w, t.w));
    }
    // scalar tail (n not divisible by 4): block 0 only
    if (blockIdx.x == 0) {
        for (int i = ((n >> 2) << 2) + tid; i < n; i += THREADS)
            atomicAdd(&s_cnt[wave][labels[i]], pack_contrib(pred[i], target[i]));
    }
    __syncthreads();

    // fold wave copies, one packed u64 global atomic per segment
    for (int s = tid; s < NSEG; s += THREADS) {
        unsigned long long tot = 0;
        #pragma unroll
        for (int w = 0; w < NWAVES; ++w) tot += s_cnt[w][s];
        if (tot) atomicAdd(&g_counts[s], tot);
    }
}

__global__ __launch_bounds__(64) void dice_finalize_kernel(
    const unsigned long long* __restrict__ g_counts,
    const int* __restrict__ nc_ptr,
    float* __restrict__ out)
{
    const int nc = *nc_ptr;          // 64
    const int tid = threadIdx.x;
    float local = 0.0f;
    for (int c = 1 + tid; c <= nc; c += 64) {
        unsigned long long v = g_counts[c];
        float in = (float)(v >> 42);
        float sp = (float)((v >> 21) & 0x1FFFFFull);
        float st = (float)(v & 0x1FFFFFull);
        float uni = sp + st;
        local += (uni > 0.0f) ? (2.0f * in / uni) : 1.0f;
    }
    #pragma unroll
    for (int off = 32; off > 0; off >>= 1)
        local += __shfl_down(local, off);
    if (tid == 0) out[0] = 1.0f - local / (float)nc;
}

extern "C" void kernel_launch(void* const* d_in, const int* in_sizes, int n_in,
                              void* d_out, int out_size, void* d_ws, size_t ws_size,
                              hipStream_t stream) {
    const float* pred   = (const float*)d_in[0];
    const float* target = (const float*)d_in[1];
    const int*   labels = (const int*)d_in[2];
    const int*   nc_ptr = (const int*)d_in[3];
    float* out = (float*)d_out;
    unsigned long long* g_counts = (unsigned long long*)d_ws;

    const int n = in_sizes[0];

    hipMemsetAsync(d_ws, 0, NSEG * sizeof(unsigned long long), stream);

    seg_count_kernel<<<BLOCKS, THREADS, 0, stream>>>(
        pred, target, labels, g_counts, n);
    dice_finalize_kernel<<<1, 64, 0, stream>>>(g_counts, nc_ptr, out);
}

// Round 5
// 214.564 us; speedup vs baseline: 1.1874x; 1.1874x over previous
//
#include <hip/hip_runtime.h>

// ClusterDiceLoss: segmented dice over 64 clusters of a 256^3 volume.
// R1 115us grid-stride. R2 432us: 8MB-strided batch aliased channels.
// R3 76us: contiguous chunks + x4 unroll (best). R4 128us: dynamic-indexed
// pipeline buffers spilled to scratch (197MB writes) — but proved memory
// path delivers 3.1 TB/s. Remaining serial resource: per-element
// ds_atomic_add_u64 on a 65-entry table (same-address lane collisions).
// R5: lane-privatized histogram — u32 tab[65][64], column = lane.
// ds_add_u32 at bank (lane mod 32): fixed 2-way aliasing = free (m136),
// near-zero same-address collisions. Packing inter<<20|sp<<10|st; per-block
// per-(seg,lane) count <= 128 << 1023, no field carry.

#define NSEG 65          // clusters 0..64 (0 = background, dropped)
#define BLOCKS 2048
#define THREADS 256

__device__ __forceinline__ unsigned int pack_contrib32(float p, float t) {
    unsigned int sp = (p != 0.0f) ? 1u : 0u;
    unsigned int st = (t != 0.0f) ? 1u : 0u;
    return ((sp & st) << 20) | (sp << 10) | st;
}

__global__ __launch_bounds__(THREADS) void seg_count_kernel(
    const float* __restrict__ pred,
    const float* __restrict__ target,
    const int* __restrict__ labels,
    unsigned long long* __restrict__ g_counts,   // [NSEG] packed u64, pre-zeroed
    int n)
{
    __shared__ unsigned int s_tab[NSEG * 64];    // 16.6 KB, column = lane
    const int tid = threadIdx.x;
    const int lane = tid & 63;

    for (int i = tid; i < NSEG * 64; i += THREADS)
        s_tab[i] = 0u;
    __syncthreads();

    const int n_vec = n >> 2;  // float4 groups
    const float4* __restrict__ p4 = (const float4*)pred;
    const float4* __restrict__ t4 = (const float4*)target;
    const int4*   __restrict__ l4 = (const int4*)labels;

    // contiguous chunk per block (R3 structure — kept identical)
    const int chunk = (n_vec + (int)gridDim.x - 1) / (int)gridDim.x;
    const int base = blockIdx.x * chunk;
    const int end = min(base + chunk, n_vec);

    int idx = base + tid;
    for (; idx + 3 * THREADS < end; idx += 4 * THREADS) {
        float4 p0 = p4[idx];
        float4 p1 = p4[idx + THREADS];
        float4 p2 = p4[idx + 2 * THREADS];
        float4 p3 = p4[idx + 3 * THREADS];
        float4 t0 = t4[idx];
        float4 t1 = t4[idx + THREADS];
        float4 t2 = t4[idx + 2 * THREADS];
        float4 t3 = t4[idx + 3 * THREADS];
        int4   l0 = l4[idx];
        int4   l1 = l4[idx + THREADS];
        int4   l2 = l4[idx + 2 * THREADS];
        int4   l3 = l4[idx + 3 * THREADS];
        atomicAdd(&s_tab[l0.x * 64 + lane], pack_contrib32(p0.x, t0.x));
        atomicAdd(&s_tab[l0.y * 64 + lane], pack_contrib32(p0.y, t0.y));
        atomicAdd(&s_tab[l0.z * 64 + lane], pack_contrib32(p0.z, t0.z));
        atomicAdd(&s_tab[l0.w * 64 + lane], pack_contrib32(p0.w, t0.w));
        atomicAdd(&s_tab[l1.x * 64 + lane], pack_contrib32(p1.x, t1.x));
        atomicAdd(&s_tab[l1.y * 64 + lane], pack_contrib32(p1.y, t1.y));
        atomicAdd(&s_tab[l1.z * 64 + lane], pack_contrib32(p1.z, t1.z));
        atomicAdd(&s_tab[l1.w * 64 + lane], pack_contrib32(p1.w, t1.w));
        atomicAdd(&s_tab[l2.x * 64 + lane], pack_contrib32(p2.x, t2.x));
        atomicAdd(&s_tab[l2.y * 64 + lane], pack_contrib32(p2.y, t2.y));
        atomicAdd(&s_tab[l2.z * 64 + lane], pack_contrib32(p2.z, t2.z));
        atomicAdd(&s_tab[l2.w * 64 + lane], pack_contrib32(p2.w, t2.w));
        atomicAdd(&s_tab[l3.x * 64 + lane], pack_contrib32(p3.x, t3.x));
        atomicAdd(&s_tab[l3.y * 64 + lane], pack_contrib32(p3.y, t3.y));
        atomicAdd(&s_tab[l3.z * 64 + lane], pack_contrib32(p3.z, t3.z));
        atomicAdd(&s_tab[l3.w * 64 + lane], pack_contrib32(p3.w, t3.w));
    }
    for (; idx < end; idx += THREADS) {
        float4 p = p4[idx];
        float4 t = t4[idx];
        int4   l = l4[idx];
        atomicAdd(&s_tab[l.x * 64 + lane], pack_contrib32(p.x, t.x));
        atomicAdd(&s_tab[l.y * 64 + lane], pack_contrib32(p.y, t.y));
        atomicAdd(&s_tab[l.z * 64 + lane], pack_contrib32(p.z, t.z));
        atomicAdd(&s_tab[l.w * 64 + lane], pack_contrib32(p.w, t.w));
    }
    // scalar tail (n not divisible by 4): block 0 only
    if (blockIdx.x == 0) {
        for (int i = ((n >> 2) << 2) + tid; i < n; i += THREADS)
            atomicAdd(&s_tab[labels[i] * 64 + lane],
                      pack_contrib32(pred[i], target[i]));
    }
    __syncthreads();

    // epilogue: threads 1..64 each sum their segment's 64 columns
    // (staggered column order -> 2-way bank aliasing only), then one
    // packed u64 global atomic per segment. Global fields are 21-bit
    // (totals ~260k << 2^21), no carry.
    if (tid >= 1 && tid < NSEG) {
        const int seg = tid;
        unsigned long long inter = 0, sp = 0, st = 0;
        #pragma unroll
        for (int j = 0; j < 64; ++j) {
            unsigned int v = s_tab[seg * 64 + ((j + tid) & 63)];
            inter += v >> 20;
            sp += (v >> 10) & 1023u;
            st += v & 1023u;
        }
        unsigned long long tot = (inter << 42) | (sp << 21) | st;
        if (tot) atomicAdd(&g_counts[seg], tot);
    }
}

__global__ __launch_bounds__(64) void dice_finalize_kernel(
    const unsigned long long* __restrict__ g_counts,
    const int* __restrict__ nc_ptr,
    float* __restrict__ out)
{
    const int nc = *nc_ptr;          // 64
    const int tid = threadIdx.x;
    float local = 0.0f;
    for (int c = 1 + tid; c <= nc; c += 64) {
        unsigned long long v = g_counts[c];
        float in = (float)(v >> 42);
        float sp = (float)((v >> 21) & 0x1FFFFFull);
        float st = (float)(v & 0x1FFFFFull);
        float uni = sp + st;
        local += (uni > 0.0f) ? (2.0f * in / uni) : 1.0f;
    }
    #pragma unroll
    for (int off = 32; off > 0; off >>= 1)
        local += __shfl_down(local, off);
    if (tid == 0) out[0] = 1.0f - local / (float)nc;
}

extern "C" void kernel_launch(void* const* d_in, const int* in_sizes, int n_in,
                              void* d_out, int out_size, void* d_ws, size_t ws_size,
                              hipStream_t stream) {
    const float* pred   = (const float*)d_in[0];
    const float* target = (const float*)d_in[1];
    const int*   labels = (const int*)d_in[2];
    const int*   nc_ptr = (const int*)d_in[3];
    float* out = (float*)d_out;
    unsigned long long* g_counts = (unsigned long long*)d_ws;

    const int n = in_sizes[0];

    hipMemsetAsync(d_ws, 0, NSEG * sizeof(unsigned long long), stream);

    seg_count_kernel<<<BLOCKS, THREADS, 0, stream>>>(
        pred, target, labels, g_counts, n);
    dice_finalize_kernel<<<1, 64, 0, stream>>>(g_counts, nc_ptr, out);
}

// Round 6
// 212.877 us; speedup vs baseline: 1.1968x; 1.0079x over previous
//
#include <hip/hip_runtime.h>

// ClusterDiceLoss: segmented dice over 64 clusters of a 256^3 volume.
// History: R1 115us grid-stride. R2 432us channel-aliased strided batch.
// R3 76us contiguous chunks + x4 unroll (best main loop). R4 128us scratch
// spill (proved 3.1 TB/s path). R5 85us lane-privatized LDS (bank conflicts
// ->0, but slower: intra-block LDS atomics were not the bottleneck).
// Standing theory for R6: 133k device-scope u64 atomics onto one 520 B
// region at block exit serialize at L2 (~35-45us tail, invisible in busy
// counters). Fix: atomic-free epilogue — per-block partial stores (1 MB ws)
// + a one-block reduce/finalize kernel. Memset dispatch deleted.

#define NSEG 65          // clusters 0..64 (0 = background, dropped)
#define NBLK 2048
#define THREADS 256
#define NWAVES 4

// Pack per-element contribution into one u64: inter<<42 | sum_p<<21 | sum_t.
// Global per-segment field totals ~260k << 2^21, so fields never carry.
__device__ __forceinline__ unsigned long long pack_contrib(float p, float t) {
    unsigned long long sp = (p != 0.0f) ? 1ull : 0ull;
    unsigned long long st = (t != 0.0f) ? 1ull : 0ull;
    return ((sp & st) << 42) | (sp << 21) | st;
}

__device__ __forceinline__ void accum4(unsigned long long (*s_cnt)[NSEG], int wave,
                                       float4 p, float4 t, int4 l) {
    atomicAdd(&s_cnt[wave][l.x], pack_contrib(p.x, t.x));
    atomicAdd(&s_cnt[wave][l.y], pack_contrib(p.y, t.y));
    atomicAdd(&s_cnt[wave][l.z], pack_contrib(p.z, t.z));
    atomicAdd(&s_cnt[wave][l.w], pack_contrib(p.w, t.w));
}

__global__ __launch_bounds__(THREADS) void seg_count_kernel(
    const float* __restrict__ pred,
    const float* __restrict__ target,
    const int* __restrict__ labels,
    unsigned long long* __restrict__ g_part,   // [NBLK][64] partials (ws)
    int n)
{
    __shared__ unsigned long long s_cnt[NWAVES][NSEG];
    const int tid = threadIdx.x;
    const int wave = tid >> 6;

    for (int i = tid; i < NWAVES * NSEG; i += THREADS)
        ((unsigned long long*)s_cnt)[i] = 0ull;
    __syncthreads();

    const int n_vec = n >> 2;  // float4 groups
    const float4* __restrict__ p4 = (const float4*)pred;
    const float4* __restrict__ t4 = (const float4*)target;
    const int4*   __restrict__ l4 = (const int4*)labels;

    // contiguous chunk per block (R3 structure — kept identical)
    const int chunk = (n_vec + (int)gridDim.x - 1) / (int)gridDim.x;
    const int base = blockIdx.x * chunk;
    const int end = min(base + chunk, n_vec);

    int idx = base + tid;
    for (; idx + 3 * THREADS < end; idx += 4 * THREADS) {
        float4 p0 = p4[idx];
        float4 p1 = p4[idx + THREADS];
        float4 p2 = p4[idx + 2 * THREADS];
        float4 p3 = p4[idx + 3 * THREADS];
        float4 t0 = t4[idx];
        float4 t1 = t4[idx + THREADS];
        float4 t2 = t4[idx + 2 * THREADS];
        float4 t3 = t4[idx + 3 * THREADS];
        int4   l0 = l4[idx];
        int4   l1 = l4[idx + THREADS];
        int4   l2 = l4[idx + 2 * THREADS];
        int4   l3 = l4[idx + 3 * THREADS];
        accum4(s_cnt, wave, p0, t0, l0);
        accum4(s_cnt, wave, p1, t1, l1);
        accum4(s_cnt, wave, p2, t2, l2);
        accum4(s_cnt, wave, p3, t3, l3);
    }
    for (; idx < end; idx += THREADS)
        accum4(s_cnt, wave, p4[idx], t4[idx], l4[idx]);

    // scalar tail (n not divisible by 4): block 0 only (dead for n=2^24)
    if (blockIdx.x == 0) {
        for (int i = ((n >> 2) << 2) + tid; i < n; i += THREADS)
            atomicAdd(&s_cnt[wave][labels[i]], pack_contrib(pred[i], target[i]));
    }
    __syncthreads();

    // atomic-free epilogue: fold wave copies, store 64 packed partials
    // contiguously (coalesced 512 B per block). Segment 0 dropped here.
    for (int s = tid; s < NSEG; s += THREADS) {
        unsigned long long tot = 0;
        #pragma unroll
        for (int w = 0; w < NWAVES; ++w) tot += s_cnt[w][s];
        if (s >= 1)
            g_part[(unsigned)blockIdx.x * 64u + (unsigned)(s - 1)] = tot;
    }
}

// One block, 1024 threads: reduce [NBLK][64] partials -> 64 dice -> scalar.
__global__ __launch_bounds__(1024) void reduce_finalize_kernel(
    const unsigned long long* __restrict__ g_part,
    const int* __restrict__ nc_ptr,
    float* __restrict__ out)
{
    __shared__ unsigned long long s_part[16][64];   // 8 KB
    const int tid = threadIdx.x;
    const int seg = tid & 63;      // 0..63 -> cluster seg+1
    const int j = tid >> 6;        // 0..15, each covers NBLK/16 = 128 blocks

    unsigned long long acc = 0;
    const int bpj = NBLK / 16;
    for (int b = j * bpj; b < (j + 1) * bpj; ++b)
        acc += g_part[(unsigned)b * 64u + (unsigned)seg];
    s_part[j][seg] = acc;
    __syncthreads();

    if (tid < 64) {
        unsigned long long tot = 0;
        #pragma unroll
        for (int jj = 0; jj < 16; ++jj) tot += s_part[jj][seg];
        float in = (float)(tot >> 42);
        float sp = (float)((tot >> 21) & 0x1FFFFFull);
        float st = (float)(tot & 0x1FFFFFull);
        float uni = sp + st;
        float local = (uni > 0.0f) ? (2.0f * in / uni) : 1.0f;
        #pragma unroll
        for (int off = 32; off > 0; off >>= 1)
            local += __shfl_down(local, off);
        if (tid == 0) out[0] = 1.0f - local / (float)(*nc_ptr);
    }
}

extern "C" void kernel_launch(void* const* d_in, const int* in_sizes, int n_in,
                              void* d_out, int out_size, void* d_ws, size_t ws_size,
                              hipStream_t stream) {
    const float* pred   = (const float*)d_in[0];
    const float* target = (const float*)d_in[1];
    const int*   labels = (const int*)d_in[2];
    const int*   nc_ptr = (const int*)d_in[3];
    float* out = (float*)d_out;
    unsigned long long* g_part = (unsigned long long*)d_ws;  // 1 MB, fully overwritten

    const int n = in_sizes[0];

    seg_count_kernel<<<NBLK, THREADS, 0, stream>>>(
        pred, target, labels, g_part, n);
    reduce_finalize_kernel<<<1, 1024, 0, stream>>>(g_part, nc_ptr, out);
}